// Round 8
// baseline (304.595 us; speedup 1.0000x reference)
//
#include <hip/hip_runtime.h>
#include <math.h>

// Problem constants (from reference setup): T=4, B=64, N=1024, P=63, D=128
#define T_STEPS 4
#define R_ROWS  65536              // B*N rows per timestep
#define M_ROWS  262144             // T*B*N total rows
#define P_DIM   63
#define D_DIM   128
#define PP      64                 // padded P (col 63 = virtual ones column in K1)

#define TILES_TOTAL (M_ROWS / 64)  // 4096 tiles of 64 rows
#define G_CHUNKS 8                 // reduce output copies consumed by stats

typedef float v4f __attribute__((ext_vector_type(4)));

// ---------------------------------------------------------------------------
// K1: per-block partial Gram  P_b = xa_b^T xa_b  (xa = x + ones column).
// (unchanged — isolate the K3 change for clean attribution)
// ---------------------------------------------------------------------------
__global__ __launch_bounds__(256) void gram_kernel(const float* __restrict__ x,
                                                   double* __restrict__ partials,
                                                   int tiles_per_block) {
    __shared__ __align__(16) float xt[2][64 * PP];
    const int tid = threadIdx.x;
    const int tj = tid & 15;       // 16 col-tiles of 4
    const int ti = tid >> 4;       // 16 row-tiles of 4

    double dacc[4][4];
#pragma unroll
    for (int a = 0; a < 4; a++)
#pragma unroll
        for (int b = 0; b < 4; b++) dacc[a][b] = 0.0;

    if (tid < 64) {                // ones column in both buffers (never overwritten)
        xt[0][tid * PP + 63] = 1.0f;
        xt[1][tid * PP + 63] = 1.0f;
    }

    const int tile0 = blockIdx.x * tiles_per_block;
    float4 reg[4];

    {
        const float4* src = (const float4*)(x + (size_t)tile0 * (64 * 63));
#pragma unroll
        for (int it = 0; it < 4; it++) {
            int k = tid + it * 256;
            reg[it] = (k < 1008) ? src[k] : make_float4(0.f, 0.f, 0.f, 0.f);
        }
    }
#pragma unroll
    for (int it = 0; it < 4; it++) {
        int k = tid + it * 256;
        if (k < 1008) {
            const float* ve = (const float*)&reg[it];
            int flat = k * 4;
#pragma unroll
            for (int e = 0; e < 4; e++) {
                int f = flat + e;
                int r = f / 63;
                int c = f - r * 63;
                xt[0][r * PP + c] = ve[e];
            }
        }
    }
    __syncthreads();

    for (int t = 0; t < tiles_per_block; t++) {
        const int cur = t & 1;
        if (t + 1 < tiles_per_block) {
            const float4* src = (const float4*)(x + (size_t)(tile0 + t + 1) * (64 * 63));
#pragma unroll
            for (int it = 0; it < 4; it++) {
                int k = tid + it * 256;
                reg[it] = (k < 1008) ? src[k] : make_float4(0.f, 0.f, 0.f, 0.f);
            }
        }

        float facc[4][4];
#pragma unroll
        for (int a = 0; a < 4; a++)
#pragma unroll
            for (int b = 0; b < 4; b++) facc[a][b] = 0.0f;

        const float* buf = xt[cur];
        for (int r = 0; r < 64; r++) {
            float4 xi = *(const float4*)&buf[r * PP + ti * 4];
            float4 xj = *(const float4*)&buf[r * PP + tj * 4];
            const float* xia = (const float*)&xi;
            const float* xja = (const float*)&xj;
#pragma unroll
            for (int a = 0; a < 4; a++)
#pragma unroll
                for (int b = 0; b < 4; b++)
                    facc[a][b] = fmaf(xia[a], xja[b], facc[a][b]);
        }
#pragma unroll
        for (int a = 0; a < 4; a++)
#pragma unroll
            for (int b = 0; b < 4; b++) dacc[a][b] += (double)facc[a][b];

        __syncthreads();
        if (t + 1 < tiles_per_block) {
            float* nbuf = xt[1 - cur];
#pragma unroll
            for (int it = 0; it < 4; it++) {
                int k = tid + it * 256;
                if (k < 1008) {
                    const float* ve = (const float*)&reg[it];
                    int flat = k * 4;
#pragma unroll
                    for (int e = 0; e < 4; e++) {
                        int f = flat + e;
                        int r = f / 63;
                        int c = f - r * 63;
                        nbuf[r * PP + c] = ve[e];
                    }
                }
            }
            __syncthreads();
        }
    }

    double* Pb = partials + (size_t)blockIdx.x * 4096;
#pragma unroll
    for (int a = 0; a < 4; a++)
#pragma unroll
        for (int b = 0; b < 4; b++)
            Pb[(ti * 4 + a) * 64 + (tj * 4 + b)] = dacc[a][b];
}

// ---------------------------------------------------------------------------
// K1b: fold nparts partials into G_CHUNKS copies (deterministic fp64 sums).
// Blocks >= 128 instead build Wt[p*128+d] = W[d*63+p] (needed by lif; folded
// here to avoid an extra launch — runs in dispatch-parallel with the folds).
// ---------------------------------------------------------------------------
__global__ __launch_bounds__(256) void reduce_kernel(const double* __restrict__ partials,
                                                     double* __restrict__ G8,
                                                     const float* __restrict__ W,
                                                     float* __restrict__ Wt,
                                                     int copies_per_chunk) {
    if (blockIdx.x >= G_CHUNKS * 16) {
        int widx = (blockIdx.x - G_CHUNKS * 16) * 256 + threadIdx.x;
        for (int j = widx; j < P_DIM * D_DIM; j += 8 * 256) {
            int p = j >> 7;
            int d = j & 127;
            Wt[j] = W[d * P_DIM + p];
        }
        return;
    }
    const int chunk = blockIdx.x >> 4;             // 0..7
    const int idx   = (blockIdx.x & 15) * 256 + threadIdx.x;  // 0..4095
    const double* src = partials + (size_t)chunk * copies_per_chunk * 4096;
    double s = 0.0;
    for (int c = 0; c < copies_per_chunk; c++)
        s += src[(size_t)c * 4096 + idx];
    G8[(size_t)chunk * 4096 + idx] = s;
}

// ---------------------------------------------------------------------------
// K2: per-channel stats (unchanged).
// ---------------------------------------------------------------------------
__global__ __launch_bounds__(64) void stats_kernel(const double* __restrict__ G,
                                                   const float* __restrict__ W,
                                                   const float* __restrict__ gamma,
                                                   const float* __restrict__ beta,
                                                   float* __restrict__ stats) {
    const int d = blockIdx.x;    // 0..127
    const int p = threadIdx.x;   // 0..63
    __shared__ float sW[64];
    sW[p] = (p < P_DIM) ? W[d * P_DIM + p] : 0.0f;
    __syncthreads();

    double inner = 0.0;
#pragma unroll
    for (int c = 0; c < G_CHUNKS; c++) {
        const double* Gr = G + (size_t)c * (64 * 64) + p * 64;
        for (int q = 0; q < 64; q++) inner += Gr[q] * (double)sW[q];
    }

    double contrib = (double)sW[p] * inner;   // row 63 has w=0 -> no effect
    double ex2M = contrib;
#pragma unroll
    for (int off = 32; off > 0; off >>= 1) ex2M += __shfl_down(ex2M, off, 64);
    double meanM = __shfl(inner, 63, 64);     // ones-row dot W_d = colsum . W_d

    if (p == 0) {
        double mean = meanM / (double)M_ROWS;
        double ex2  = ex2M  / (double)M_ROWS;
        double var  = ex2 - mean * mean;
        float varf  = (float)var;
        float vpe   = varf + 1e-5f;                 // ref: fp32 var + fp32 eps
        float invstd = (float)(1.0 / sqrt((double)vpe));
        stats[d * 4 + 0] = (float)mean;
        stats[d * 4 + 1] = invstd;
        stats[d * 4 + 2] = gamma[d];
        stats[d * 4 + 3] = beta[d];
    }
}

// ---------------------------------------------------------------------------
// K3 r17: OCCUPANCY fix.  r16 profile: lif=100.6us, VALU-busy ~41us (FMA
// floor 27us), conflicts trivial -> ~59us is STALL, hidden poorly at the
// LDS-capped 3 blocks/CU (48.6KB).  Change: each block covers HALF of D
// (64 ch): sw 63x64 = 15.75KB, block LDS total 32512B <= 32768 -> 5
// blocks/CU (20 waves) at VGPR<=64, 4 blocks (16 waves) otherwise; either
// way >=+33% resident waves.  acc[4][4]=16 floats, per-thread live ~50-70
// (LESS than r10's 92 -> no remat/spill risk, the r12-r15 failure mode).
// Paired blocks (half=bid&1) share the x tile back-to-back -> L2/L3 hit.
// Per (row,ch) fmaf chain still ascending p=0..62 -> h bitwise identical.
// ---------------------------------------------------------------------------
#define LIF_ROWS 16
#define SX_STRIDE 64
__global__ __launch_bounds__(256) void lif_kernel(const float* __restrict__ x,
                                                  const float* __restrict__ Wt,
                                                  const float* __restrict__ stats,
                                                  float* __restrict__ out) {
    __shared__ __align__(16) float sw[P_DIM * 64];                     // 16128 B
    __shared__ __align__(16) float sx[T_STEPS * LIF_ROWS * SX_STRIDE]; // 16384 B
    const int tid = threadIdx.x;
    const int half = blockIdx.x & 1;           // which 64-channel half of D
    const int r0 = (blockIdx.x >> 1) * LIF_ROWS;

    // stage half of Wt: 1008 v4f, coalesced global reads, linear ds writes
    {
        const float4* wt4 = (const float4*)Wt;   // [63][32] float4
        float4* sw4 = (float4*)sw;               // [63][16] float4
        const int hbase = half * 16;
#pragma unroll
        for (int i = 0; i < 4; i++) {
            int j = tid + i * 256;
            if (j < 1008) {
                int p = j >> 4, cq = j & 15;
                sw4[j] = wt4[p * 32 + hbase + cq];
            }
        }
    }

    // stage x: identical to r10 (flat coalesced nontemporal b128, scatter
    // into stride-64 rows)
    const int seg = tid >> 6;      // timestep
    const int lane = tid & 63;
    const v4f* src = (const v4f*)(x + ((size_t)seg * R_ROWS + r0) * P_DIM);
#pragma unroll
    for (int kk = 0; kk < 4; kk++) {
        int k = lane + kk * 64;    // < 256; 252 valid
        v4f v;
        if (k < 252) v = __builtin_nontemporal_load(&src[k]);
        if (k < 252) {
            int flat = k * 4;
#pragma unroll
            for (int e = 0; e < 4; e++) {
                int f = flat + e;
                int r = f / 63;
                int c = f - r * 63;
                sx[(seg * LIF_ROWS + r) * SX_STRIDE + c] = v[e];
            }
        }
    }
    __syncthreads();

    const int td = tid & 15;      // 16 channel-tiles of 4 (within the half)
    const int tr = tid >> 4;      // 16 rows, one per thread
    const int dl = td * 4;        // local channel base in [0,64)

    float acc[T_STEPS][4];
#pragma unroll
    for (int t = 0; t < T_STEPS; t++)
#pragma unroll
        for (int j = 0; j < 4; j++) acc[t][j] = 0.0f;

    // main loop: 15 p-quads, fully unrolled (imm ds offsets).
    // per pq: 4 w b128 (16 lanes x 16B contiguous) + 4 x b128 (4-address
    // broadcast) feed 64 FMAs.
#pragma unroll
    for (int pq = 0; pq < 15; pq++) {
        const int p = pq * 4;
        float4 w0 = *(const float4*)&sw[(p + 0) * 64 + dl];
        float4 w1 = *(const float4*)&sw[(p + 1) * 64 + dl];
        float4 w2 = *(const float4*)&sw[(p + 2) * 64 + dl];
        float4 w3 = *(const float4*)&sw[(p + 3) * 64 + dl];
        float4 xv[T_STEPS];
#pragma unroll
        for (int t = 0; t < T_STEPS; t++)
            xv[t] = *(const float4*)&sx[(t * LIF_ROWS + tr) * SX_STRIDE + p];
#pragma unroll
        for (int t = 0; t < T_STEPS; t++) {
            float* a = acc[t];
            a[0] = fmaf(xv[t].x, w0.x, a[0]);
            a[1] = fmaf(xv[t].x, w0.y, a[1]);
            a[2] = fmaf(xv[t].x, w0.z, a[2]);
            a[3] = fmaf(xv[t].x, w0.w, a[3]);
            a[0] = fmaf(xv[t].y, w1.x, a[0]);
            a[1] = fmaf(xv[t].y, w1.y, a[1]);
            a[2] = fmaf(xv[t].y, w1.z, a[2]);
            a[3] = fmaf(xv[t].y, w1.w, a[3]);
            a[0] = fmaf(xv[t].z, w2.x, a[0]);
            a[1] = fmaf(xv[t].z, w2.y, a[1]);
            a[2] = fmaf(xv[t].z, w2.z, a[2]);
            a[3] = fmaf(xv[t].z, w2.w, a[3]);
            a[0] = fmaf(xv[t].w, w3.x, a[0]);
            a[1] = fmaf(xv[t].w, w3.y, a[1]);
            a[2] = fmaf(xv[t].w, w3.z, a[2]);
            a[3] = fmaf(xv[t].w, w3.w, a[3]);
        }
    }
    // tail: p = 60, 61, 62 (same ascending order)
#pragma unroll
    for (int p = 60; p < 63; p++) {
        float4 w4 = *(const float4*)&sw[p * 64 + dl];
#pragma unroll
        for (int t = 0; t < T_STEPS; t++) {
            float xvs = sx[(t * LIF_ROWS + tr) * SX_STRIDE + p];
            float* a = acc[t];
            a[0] = fmaf(xvs, w4.x, a[0]);
            a[1] = fmaf(xvs, w4.y, a[1]);
            a[2] = fmaf(xvs, w4.z, a[2]);
            a[3] = fmaf(xvs, w4.w, a[3]);
        }
    }

    // epilogue: BN affine (ref op order) + LIF scan; nontemporal b128 stores
    const int row = r0 + tr;
    const int dg = half * 64 + dl;            // global channel base
    float sval[T_STEPS][4];
#pragma unroll
    for (int j = 0; j < 4; j++) {
        float4 st = ((const float4*)stats)[dg + j];  // mean, invstd, gamma, beta
        float v = 0.0f;
#pragma unroll
        for (int t = 0; t < T_STEPS; t++) {
            float hn = (acc[t][j] - st.x) * st.y;
            hn = hn * st.z;
            hn = hn + st.w;
            v = v + (hn - v) * 0.5f;           // == v + (x-v)/2, exact
            float s = (v >= 1.0f) ? 1.0f : 0.0f;  // (v-1>=0) sign-exact
            sval[t][j] = s;
            if (s != 0.0f) v = 0.0f;           // hard reset
        }
    }
#pragma unroll
    for (int t = 0; t < T_STEPS; t++) {
        v4f o = {sval[t][0], sval[t][1], sval[t][2], sval[t][3]};
        __builtin_nontemporal_store(
            o, (v4f*)&out[((size_t)t * R_ROWS + row) * D_DIM + dg]);
    }
}

// ---------------------------------------------------------------------------
extern "C" void kernel_launch(void* const* d_in, const int* in_sizes, int n_in,
                              void* d_out, int out_size, void* d_ws, size_t ws_size,
                              hipStream_t stream) {
    const float* x     = (const float*)d_in[0];
    const float* W     = (const float*)d_in[1];
    const float* gamma = (const float*)d_in[2];
    const float* beta  = (const float*)d_in[3];
    float* out = (float*)d_out;

    // pick partial count by available workspace (power of 2, 64..512)
    const size_t fixed = (size_t)G_CHUNKS * 4096 * 8 + 2048 + 32768 + 4096;
    int nparts = 512;
    while (nparts > 64 && (size_t)nparts * 4096 * 8 + fixed > ws_size) nparts >>= 1;
    const int tiles_per_block = TILES_TOTAL / nparts;

    double* partials = (double*)d_ws;
    double* G8       = (double*)((char*)d_ws + (size_t)nparts * 4096 * 8);
    float*  stats    = (float*)((char*)G8 + (size_t)G_CHUNKS * 4096 * 8);
    float*  Wt       = (float*)((char*)stats + 2048);

    gram_kernel<<<nparts, 256, 0, stream>>>(x, partials, tiles_per_block);
    reduce_kernel<<<G_CHUNKS * 16 + 8, 256, 0, stream>>>(partials, G8, W, Wt,
                                                         nparts / G_CHUNKS);
    stats_kernel<<<D_DIM, 64, 0, stream>>>(G8, W, gamma, beta, stats);
    lif_kernel<<<R_ROWS / LIF_ROWS * 2, 256, 0, stream>>>(x, Wt, stats, out);
}